// Round 1
// baseline (1301.219 us; speedup 1.0000x reference)
//
#include <hip/hip_runtime.h>

#define MIN_NORM 1e-15f

__device__ __forceinline__ float wsum(float v) {
#pragma unroll
    for (int m = 32; m >= 1; m >>= 1) v += __shfl_xor(v, m, 64);
    return v;
}

// One wave (64 lanes) per edge; lane = dimension.
__global__ __launch_bounds__(256) void rgat_edge_kernel(
    const float* __restrict__ e,      // [N,64] current entity embeddings
    const float* __restrict__ rel,    // [32,64]
    const int*   __restrict__ head,   // [E]
    const int*   __restrict__ tail,   // [E]
    const int*   __restrict__ etype,  // [E] 1-based
    float*       __restrict__ sums,   // [N,64] scatter-add target (pre-zeroed)
    int E)
{
    int wid  = (int)((blockIdx.x * blockDim.x + threadIdx.x) >> 6);
    int lane = threadIdx.x & 63;
    if (wid >= E) return;

    int hi = head[wid];
    int ti = tail[wid];
    int ri = etype[wid] - 1;

    float h = e[(size_t)hi * 64 + lane];
    float t = e[(size_t)ti * 64 + lane];
    float r = rel[(size_t)ri * 64 + lane];
    float trl = t + r;

    // ---- the only 6 wave reductions ----
    float hh   = wsum(h * h);
    float tt   = wsum(t * t);
    float rr   = wsum(r * r);
    float ntr2 = wsum(trl * trl);
    float ht   = wsum(h * t);
    float hr   = wsum(h * r);

    // p = expmap0(h) = tanh(|h|) * h/|h|
    float nh  = fmaxf(sqrtf(hh), MIN_NORM);
    float th  = tanhf(nh);
    float scp = th / nh;                 // p = scp*h
    float p2  = th * th;                 // |p|^2
    float lam_inv = fmaxf(1.f - p2, MIN_NORM);   // = 2/lam (clipped like ref)
    float lam     = 2.f / lam_inv;

    // yt = tanh(0.5*lam*|t|) * t/|t|
    float nt  = fmaxf(sqrtf(tt), MIN_NORM);
    float tht = tanhf(0.5f * lam * nt);
    float sct = tht / nt;                // yt = sct*t
    float y2t = tht * tht;
    float xyt = scp * sct * ht;          // p.yt

    // yr = tanh(0.5*lam*|r|) * r/|r|
    float nr  = fmaxf(sqrtf(rr), MIN_NORM);
    float thr = tanhf(0.5f * lam * nr);
    float scr = thr / nr;                // yr = scr*r
    float y2r = thr * thr;
    float xyr = scp * scr * hr;          // p.yr

    // a = hyper_tail = mobius_add(p, yt)
    float alt  = 1.f + 2.f * xyt + y2t;
    float bet  = 1.f - p2;
    float dent = fmaxf(1.f + 2.f * xyt + p2 * y2t, MIN_NORM);
    float idt  = 1.f / dent;
    float a2 = (alt * alt * p2 + 2.f * alt * bet * xyt + bet * bet * y2t) * idt * idt;
    float pa = (alt * p2 + bet * xyt) * idt;   // p.a

    // b = hyper_rel = mobius_add(p, yr)
    float alr  = 1.f + 2.f * xyr + y2r;
    float denr = fmaxf(1.f + 2.f * xyr + p2 * y2r, MIN_NORM);
    float idr  = 1.f / denr;
    float b2 = (alr * alr * p2 + 2.f * alr * bet * xyr + bet * bet * y2r) * idr * idr;
    float pb = (alr * p2 + bet * xyr) * idr;   // p.b

    // a.b via t.r from parallelogram identity
    float trd  = 0.5f * (ntr2 - tt - rr);      // t.r
    float ytyr = sct * scr * trd;              // yt.yr
    float ab = (alt * alr * p2 + alt * bet * xyr + bet * alr * xyt + bet * bet * ytyr) * idt * idr;

    // m = mobius_add(a, b)
    float am   = 1.f + 2.f * ab + b2;
    float bm   = 1.f - a2;
    float denm = fmaxf(1.f + 2.f * ab + a2 * b2, MIN_NORM);
    float idm  = 1.f / denm;
    float m2  = (am * am * a2 + 2.f * am * bm * ab + bm * bm * b2) * idm * idm;
    float pmv = (am * pa + bm * pb) * idm;     // p.m

    // per-lane vectors
    float p_l = scp * h;
    float a_l = (alt * p_l + bet * (sct * t)) * idt;
    float b_l = (alr * p_l + bet * (scr * r)) * idr;
    float m_l = (am * a_l + bm * b_l) * idm;

    // project(m)
    float nm = fmaxf(sqrtf(m2), MIN_NORM);
    const float maxn = 1.f - 4e-3f;
    if (nm > maxn) {                 // wave-uniform branch
        float sc = maxn / nm;
        m_l *= sc;
        m2  *= sc * sc;
        pmv *= sc;
    }

    // sub = mobius_add(-p, m);  logmap
    float cs   = 1.f - 2.f * pmv + m2;
    float dsf  = 1.f - p2;
    float dens = fmaxf(1.f - 2.f * pmv + p2 * m2, MIN_NORM);
    float ids  = 1.f / dens;
    float s_l = (cs * (-p_l) + dsf * m_l) * ids;
    float s2  = (cs * cs * p2 - 2.f * cs * dsf * pmv + dsf * dsf * m2) * ids * ids;
    float ns  = fmaxf(sqrtf(s2), MIN_NORM);
    float xa  = fminf(ns, 1.f - 1e-7f);
    float ath = 0.5f * logf((1.f + xa) / (1.f - xa));
    float lg_l = lam_inv * ath / ns * s_l;

    // ricci * 1e-7, relu
    float ricci_l = trl / fmaxf(sqrtf(ntr2), 1e-12f);
    float res_l = fmaxf(lg_l + 1e-7f * ricci_l, 0.f);

    atomicAdd(&sums[(size_t)hi * 64 + lane], res_l);
}

// One wave per entity: normalize(sums) (count division cancels under l2-norm),
// residual update, optionally write normalized e for the next hop.
__global__ __launch_bounds__(256) void rgat_entity_kernel(
    const float* __restrict__ sums,
    const float* __restrict__ res_in,
    float*       __restrict__ res_out,
    float*       __restrict__ e_out,   // may equal sums (in-place) or null
    int N)
{
    int wid  = (int)((blockIdx.x * blockDim.x + threadIdx.x) >> 6);
    int lane = threadIdx.x & 63;
    if (wid >= N) return;
    size_t idx = (size_t)wid * 64 + lane;

    float v  = sums[idx];
    float n2 = wsum(v * v);
    v = v / fmaxf(sqrtf(n2), 1e-12f);

    if (e_out) e_out[idx] = v;
    res_out[idx] = 0.5f * res_in[idx] + v;
}

extern "C" void kernel_launch(void* const* d_in, const int* in_sizes, int n_in,
                              void* d_out, int out_size, void* d_ws, size_t ws_size,
                              hipStream_t stream)
{
    const float* ent   = (const float*)d_in[0];   // [N,64]
    const float* rel   = (const float*)d_in[1];   // [32,64]
    const int*   eidx  = (const int*)d_in[2];     // [2,E]
    const int*   etype = (const int*)d_in[3];     // [E]

    int E = in_sizes[3];
    int N = in_sizes[0] / 64;
    const int* head = eidx;
    const int* tail = eidx + E;

    float* A = (float*)d_ws;                  // hop-1 sums, then normalized e
    float* B = A + (size_t)N * 64;            // hop-2 sums
    size_t embBytes = (size_t)N * 64 * sizeof(float);

    hipMemsetAsync(d_ws, 0, 2 * embBytes, stream);

    dim3 blk(256);
    int edgeGrid = (E + 3) / 4;   // 4 waves/block, 1 wave per edge
    int entGrid  = (N + 3) / 4;

    float* out = (float*)d_out;

    // hop 1
    rgat_edge_kernel<<<edgeGrid, blk, 0, stream>>>(ent, rel, head, tail, etype, A, E);
    rgat_entity_kernel<<<entGrid, blk, 0, stream>>>(A, ent, out, A, N);
    // hop 2 (reads normalized e from A, accumulates into B)
    rgat_edge_kernel<<<edgeGrid, blk, 0, stream>>>(A, rel, head, tail, etype, B, E);
    rgat_entity_kernel<<<entGrid, blk, 0, stream>>>(B, out, out, nullptr, N);
}